// Round 3
// baseline (112.121 us; speedup 1.0000x reference)
//
#include <hip/hip_runtime.h>

#define T_TOKENS 8192
#define MAX_NODES 8192
#define FEAT 256
#define NCHUNKS 1024
#define CHUNK 8                  // T_TOKENS / NCHUNKS
#define NSUPER 32
#define SUPER 32                 // chunks per supergroup
#define LIST_CAP 2048            // events/chunk cap (expected ~18, huge margin)
#define EV_STRIDE LIST_CAP
#define FLAG_STRIDE 16           // ints -> one flag per 64B line
#define FLAG_MAGIC 0x1B7F00D5    // poison-proof "published" value
#define FLAG_PAD 64

// entry = (node << 4) | (local_row << 1) | sign, local_row in [0,8)
#define APPLY_EVENT(eV, vV)                          \
    {                                                \
        const float sv_ = ((eV) & 1) ? -(vV) : (vV); \
        const int lr_ = ((eV) >> 1) & 7;             \
        d0 += (lr_ == 0) ? sv_ : 0.f;                \
        d1 += (lr_ == 1) ? sv_ : 0.f;                \
        d2 += (lr_ == 2) ? sv_ : 0.f;                \
        d3 += (lr_ == 3) ? sv_ : 0.f;                \
        d4 += (lr_ == 4) ? sv_ : 0.f;                \
        d5 += (lr_ == 5) ? sv_ : 0.f;                \
        d6 += (lr_ == 6) ? sv_ : 0.f;                \
        d7 += (lr_ == 7) ? sv_ : 0.f;                \
    }

// Device-coherent (cross-XCD safe) helpers for SAME-KERNEL producer/consumer.
__device__ __forceinline__ float agld(const float* p) {
    return __hip_atomic_load((const float*)p, __ATOMIC_RELAXED, __HIP_MEMORY_SCOPE_AGENT);
}
__device__ __forceinline__ void agst(float* p, float v) {
    __hip_atomic_store(p, v, __ATOMIC_RELAXED, __HIP_MEMORY_SCOPE_AGENT);
}

// column-f sum over n rows of [n][FEAT], plain loads (cross-KERNEL data), 8 in flight
__device__ __forceinline__ float sum_rows_plain(const float* p, int n, int f) {
    float r0 = 0.f, r1 = 0.f, r2 = 0.f, r3 = 0.f;
    float r4 = 0.f, r5 = 0.f, r6 = 0.f, r7 = 0.f;
    int i = 0;
    for (; i + 8 <= n; i += 8) {
        r0 += p[(size_t)(i + 0) * FEAT + f];
        r1 += p[(size_t)(i + 1) * FEAT + f];
        r2 += p[(size_t)(i + 2) * FEAT + f];
        r3 += p[(size_t)(i + 3) * FEAT + f];
        r4 += p[(size_t)(i + 4) * FEAT + f];
        r5 += p[(size_t)(i + 5) * FEAT + f];
        r6 += p[(size_t)(i + 6) * FEAT + f];
        r7 += p[(size_t)(i + 7) * FEAT + f];
    }
    for (; i < n; ++i) r0 += p[(size_t)i * FEAT + f];
    return ((r0 + r1) + (r2 + r3)) + ((r4 + r5) + (r6 + r7));
}

// same but agent-scope loads (data written by other blocks in THIS kernel)
__device__ __forceinline__ float sum_rows_agent(const float* p, int n, int f) {
    float r0 = 0.f, r1 = 0.f, r2 = 0.f, r3 = 0.f;
    float r4 = 0.f, r5 = 0.f, r6 = 0.f, r7 = 0.f;
    int i = 0;
    for (; i + 8 <= n; i += 8) {
        r0 += agld(p + (size_t)(i + 0) * FEAT + f);
        r1 += agld(p + (size_t)(i + 1) * FEAT + f);
        r2 += agld(p + (size_t)(i + 2) * FEAT + f);
        r3 += agld(p + (size_t)(i + 3) * FEAT + f);
        r4 += agld(p + (size_t)(i + 4) * FEAT + f);
        r5 += agld(p + (size_t)(i + 5) * FEAT + f);
        r6 += agld(p + (size_t)(i + 6) * FEAT + f);
        r7 += agld(p + (size_t)(i + 7) * FEAT + f);
    }
    for (; i < n; ++i) r0 += agld(p + (size_t)i * FEAT + f);
    return ((r0 + r1) + (r2 + r3)) + ((r4 + r5) + (r6 + r7));
}

// ---------------------------------------------------------------------------
// K1: classify + gather-once. Block c scans only the rounds that can hold
// valid nodes (6 of 8 at num_nodes=6000), builds its event list in LDS,
// gathers the ~18 signed emb rows ONCE into d0..d7, then writes:
//   colsum[c]  = total chunk delta
//   out[c*8+r] = chunk-LOCAL cumsum (d0+..+dr)  -- K2 just adds `run`
// Block 0 also zeroes the 32 padded supergroup flags (replaces the memset
// dispatch; visible to K2 via the kernel boundary).
// ---------------------------------------------------------------------------
__global__ __launch_bounds__(FEAT) void k1_classify(
    const float* __restrict__ emb,
    const int* __restrict__ starts,
    const int* __restrict__ ends,
    const int* __restrict__ num_nodes_p,
    float* __restrict__ colsum,
    int* __restrict__ sflag,
    float* __restrict__ out) {
    __shared__ int s_list[LIST_CAP];   // 8 KB
    __shared__ int s_cnt;
    const int c = blockIdx.x;
    const int tid = threadIdx.x;
    const int f = tid;
    const int num_nodes = *num_nodes_p;
    const int row_lo = c * CHUNK;
    const int row_hi = row_lo + CHUNK;
    const int4* starts4 = (const int4*)starts;
    const int4* ends4 = (const int4*)ends;

    if (c == 0 && tid < NSUPER) sflag[tid * FLAG_STRIDE] = 0;

    if (tid == 0) s_cnt = 0;
    __syncthreads();
    const int R = min(MAX_NODES / (4 * FEAT), (num_nodes + 1023) >> 10);
    for (int r = 0; r < R; ++r) {
        const int vec = r * FEAT + tid;
        const int4 s4 = starts4[vec];
        const int4 e4 = ends4[vec];
        const int sv[4] = {s4.x, s4.y, s4.z, s4.w};
        const int ev[4] = {e4.x, e4.y, e4.z, e4.w};
        const int nb = vec * 4;
#pragma unroll
        for (int k = 0; k < 4; ++k) {
            const int node = nb + k;
            const int s = sv[k];
            const int e = ev[k];
            if (node < num_nodes && s <= e && s < T_TOKENS && e >= 0) {
                const int sc = s < 0 ? 0 : s;
                if (sc >= row_lo && sc < row_hi) {
                    int p = atomicAdd(&s_cnt, 1);
                    if (p < LIST_CAP) s_list[p] = (node << 4) | ((sc - row_lo) << 1);
                }
                const int e1 = e + 1;
                if (e1 < T_TOKENS && e1 >= row_lo && e1 < row_hi) {
                    int p = atomicAdd(&s_cnt, 1);
                    if (p < LIST_CAP) s_list[p] = (node << 4) | ((e1 - row_lo) << 1) | 1;
                }
            }
        }
    }
    __syncthreads();
    const int cnt = min(s_cnt, LIST_CAP);

    float d0 = 0.f, d1 = 0.f, d2 = 0.f, d3 = 0.f;
    float d4 = 0.f, d5 = 0.f, d6 = 0.f, d7 = 0.f;
    {
        int j = 0;
        for (; j + 8 <= cnt; j += 8) {
            const int e0 = s_list[j + 0], e1 = s_list[j + 1];
            const int e2 = s_list[j + 2], e3 = s_list[j + 3];
            const int e4_ = s_list[j + 4], e5 = s_list[j + 5];
            const int e6 = s_list[j + 6], e7 = s_list[j + 7];
            const float v0 = emb[(size_t)(e0 >> 4) * FEAT + f];
            const float v1 = emb[(size_t)(e1 >> 4) * FEAT + f];
            const float v2 = emb[(size_t)(e2 >> 4) * FEAT + f];
            const float v3 = emb[(size_t)(e3 >> 4) * FEAT + f];
            const float v4 = emb[(size_t)(e4_ >> 4) * FEAT + f];
            const float v5 = emb[(size_t)(e5 >> 4) * FEAT + f];
            const float v6 = emb[(size_t)(e6 >> 4) * FEAT + f];
            const float v7 = emb[(size_t)(e7 >> 4) * FEAT + f];
            APPLY_EVENT(e0, v0);
            APPLY_EVENT(e1, v1);
            APPLY_EVENT(e2, v2);
            APPLY_EVENT(e3, v3);
            APPLY_EVENT(e4_, v4);
            APPLY_EVENT(e5, v5);
            APPLY_EVENT(e6, v6);
            APPLY_EVENT(e7, v7);
        }
        for (; j < cnt; ++j) {
            const int e0 = s_list[j];
            const float v0 = emb[(size_t)(e0 >> 4) * FEAT + f];
            APPLY_EVENT(e0, v0);
        }
    }
    colsum[(size_t)c * FEAT + f] = ((d0 + d1) + (d2 + d3)) + ((d4 + d5) + (d6 + d7));

    // chunk-local cumsum straight into out
    float* o = out + (size_t)c * CHUNK * FEAT + f;
    float run = 0.f;
    run += d0; o[0 * FEAT] = run;
    run += d1; o[1 * FEAT] = run;
    run += d2; o[2 * FEAT] = run;
    run += d3; o[3 * FEAT] = run;
    run += d4; o[4 * FEAT] = run;
    run += d5; o[5 * FEAT] = run;
    run += d6; o[6 * FEAT] = run;
    run += d7; o[7 * FEAT] = run;
}

// ---------------------------------------------------------------------------
// K2: prefix + apply. Zero LDS -> 8 blocks/CU, all 1024 trivially resident.
// Blocks 0..31 (dispatched first) publish supersum[c] from 32 colsum rows,
// release a padded per-line flag. Every block polls only the <=31 flags it
// needs (31 distinct 64B lines), computes run = sum(supersum[<sg]) +
// sum(colsum in-group <lc), then out[row] += run (streaming RMW).
// Only cross-block edge inside this kernel is 32-wide.
// ---------------------------------------------------------------------------
__global__ __launch_bounds__(FEAT) void k2_scan(
    const float* __restrict__ colsum,
    float* __restrict__ supersum,
    int* __restrict__ sflag,
    float* __restrict__ out) {
    const int c = blockIdx.x;
    const int tid = threadIdx.x;
    const int f = tid;
    const int sg = c >> 5;
    const int lc = c & 31;
    const int base = sg * SUPER;

    if (c < NSUPER) {
        // publisher duty for supergroup c (colsum is K1 data: plain loads)
        const float incl = sum_rows_plain(colsum + (size_t)c * SUPER * FEAT, SUPER, f);
        agst(&supersum[(size_t)c * FEAT + f], incl);
        __syncthreads();   // all lanes' supersum stores drained (vmcnt 0)
        if (tid == 0)
            __hip_atomic_store(&sflag[c * FLAG_STRIDE], FLAG_MAGIC,
                               __ATOMIC_RELEASE, __HIP_MEMORY_SCOPE_AGENT);
    }

    float run;
    if (sg == 0) {
        run = sum_rows_plain(colsum, lc, f);
    } else {
        if (tid < sg) {
            while (__hip_atomic_load(&sflag[tid * FLAG_STRIDE],
                                     __ATOMIC_ACQUIRE, __HIP_MEMORY_SCOPE_AGENT) != FLAG_MAGIC)
                __builtin_amdgcn_s_sleep(8);
        }
        __syncthreads();
        run = sum_rows_agent(supersum, sg, f) +
              sum_rows_plain(colsum + (size_t)base * FEAT, lc, f);
    }

    // streaming RMW: out already holds chunk-local cumsums from K1
    float* o = out + (size_t)c * CHUNK * FEAT + f;
    const float v0 = o[0 * FEAT];
    const float v1 = o[1 * FEAT];
    const float v2 = o[2 * FEAT];
    const float v3 = o[3 * FEAT];
    const float v4 = o[4 * FEAT];
    const float v5 = o[5 * FEAT];
    const float v6 = o[6 * FEAT];
    const float v7 = o[7 * FEAT];
    o[0 * FEAT] = run + v0;
    o[1 * FEAT] = run + v1;
    o[2 * FEAT] = run + v2;
    o[3 * FEAT] = run + v3;
    o[4 * FEAT] = run + v4;
    o[5 * FEAT] = run + v5;
    o[6 * FEAT] = run + v6;
    o[7 * FEAT] = run + v7;
}

// ---------------------------------------------------------------------------
// Fallback path (verified 84 µs 3-dispatch version) if the occupancy gate
// for K2's flag design fails.
// ---------------------------------------------------------------------------
__global__ __launch_bounds__(FEAT) void classify_colsum_kernel(
    const float* __restrict__ emb,
    const int* __restrict__ starts,
    const int* __restrict__ ends,
    const int* __restrict__ num_nodes_p,
    float* __restrict__ colsum,
    float* __restrict__ supersum,
    int* __restrict__ evcnt,
    int* __restrict__ evbuf) {
    __shared__ int s_list[LIST_CAP];
    __shared__ int s_cnt;
    const int c = blockIdx.x;
    const int tid = threadIdx.x;
    const int f = tid;
    const int num_nodes = *num_nodes_p;
    const int row_lo = c * CHUNK;
    const int row_hi = row_lo + CHUNK;
    const int4* starts4 = (const int4*)starts;
    const int4* ends4 = (const int4*)ends;

    if (tid == 0) s_cnt = 0;
    __syncthreads();
#pragma unroll
    for (int r = 0; r < MAX_NODES / (4 * FEAT); ++r) {
        const int vec = r * FEAT + tid;
        const int4 s4 = starts4[vec];
        const int4 e4 = ends4[vec];
        const int sv[4] = {s4.x, s4.y, s4.z, s4.w};
        const int ev[4] = {e4.x, e4.y, e4.z, e4.w};
        const int nb = vec * 4;
#pragma unroll
        for (int k = 0; k < 4; ++k) {
            const int node = nb + k;
            const int s = sv[k];
            const int e = ev[k];
            if (node < num_nodes && s <= e && s < T_TOKENS && e >= 0) {
                const int sc = s < 0 ? 0 : s;
                if (sc >= row_lo && sc < row_hi) {
                    int p = atomicAdd(&s_cnt, 1);
                    if (p < LIST_CAP) s_list[p] = (node << 4) | ((sc - row_lo) << 1);
                }
                const int e1 = e + 1;
                if (e1 < T_TOKENS && e1 >= row_lo && e1 < row_hi) {
                    int p = atomicAdd(&s_cnt, 1);
                    if (p < LIST_CAP) s_list[p] = (node << 4) | ((e1 - row_lo) << 1) | 1;
                }
            }
        }
    }
    __syncthreads();
    const int cnt = min(s_cnt, LIST_CAP);

    int* evb = evbuf + (size_t)c * EV_STRIDE;
    for (int j = tid; j < cnt; j += FEAT) evb[j] = s_list[j];
    if (tid == 0) evcnt[c] = cnt;

    float acc = 0.f;
    int j = 0;
    for (; j + 8 <= cnt; j += 8) {
        const int e0 = s_list[j + 0], e1 = s_list[j + 1];
        const int e2 = s_list[j + 2], e3 = s_list[j + 3];
        const int e4_ = s_list[j + 4], e5 = s_list[j + 5];
        const int e6 = s_list[j + 6], e7 = s_list[j + 7];
        const float v0 = emb[(size_t)(e0 >> 4) * FEAT + f];
        const float v1 = emb[(size_t)(e1 >> 4) * FEAT + f];
        const float v2 = emb[(size_t)(e2 >> 4) * FEAT + f];
        const float v3 = emb[(size_t)(e3 >> 4) * FEAT + f];
        const float v4 = emb[(size_t)(e4_ >> 4) * FEAT + f];
        const float v5 = emb[(size_t)(e5 >> 4) * FEAT + f];
        const float v6 = emb[(size_t)(e6 >> 4) * FEAT + f];
        const float v7 = emb[(size_t)(e7 >> 4) * FEAT + f];
        acc += (e0 & 1) ? -v0 : v0;
        acc += (e1 & 1) ? -v1 : v1;
        acc += (e2 & 1) ? -v2 : v2;
        acc += (e3 & 1) ? -v3 : v3;
        acc += (e4_ & 1) ? -v4 : v4;
        acc += (e5 & 1) ? -v5 : v5;
        acc += (e6 & 1) ? -v6 : v6;
        acc += (e7 & 1) ? -v7 : v7;
    }
    for (; j < cnt; ++j) {
        const int e0 = s_list[j];
        const float v0 = emb[(size_t)(e0 >> 4) * FEAT + f];
        acc += (e0 & 1) ? -v0 : v0;
    }
    colsum[(size_t)c * FEAT + f] = acc;
    atomicAdd(&supersum[(size_t)(c >> 5) * FEAT + f], acc);
}

__global__ __launch_bounds__(FEAT) void scan_kernel(
    const float* __restrict__ emb,
    const float* __restrict__ colsum,
    const float* __restrict__ supersum,
    const int* __restrict__ evcnt,
    const int* __restrict__ evbuf,
    float* __restrict__ out) {
    const int c = blockIdx.x;
    const int f = threadIdx.x;
    const int sg = c >> 5;

    const int cnt = evcnt[c];
    const int* evb = evbuf + (size_t)c * EV_STRIDE;

    float run = sum_rows_plain(supersum, sg, f) +
                sum_rows_plain(colsum + (size_t)sg * SUPER * FEAT, c & 31, f);

    float d0 = 0.f, d1 = 0.f, d2 = 0.f, d3 = 0.f;
    float d4 = 0.f, d5 = 0.f, d6 = 0.f, d7 = 0.f;
    int j = 0;
    for (; j + 4 <= cnt; j += 4) {
        const int e0 = evb[j + 0], e1 = evb[j + 1];
        const int e2 = evb[j + 2], e3 = evb[j + 3];
        const float v0 = emb[(size_t)(e0 >> 4) * FEAT + f];
        const float v1 = emb[(size_t)(e1 >> 4) * FEAT + f];
        const float v2 = emb[(size_t)(e2 >> 4) * FEAT + f];
        const float v3 = emb[(size_t)(e3 >> 4) * FEAT + f];
        APPLY_EVENT(e0, v0);
        APPLY_EVENT(e1, v1);
        APPLY_EVENT(e2, v2);
        APPLY_EVENT(e3, v3);
    }
    for (; j < cnt; ++j) {
        const int e0 = evb[j];
        const float v0 = emb[(size_t)(e0 >> 4) * FEAT + f];
        APPLY_EVENT(e0, v0);
    }

    float* o = out + (size_t)c * CHUNK * FEAT + f;
    run += d0; o[0 * FEAT] = run;
    run += d1; o[1 * FEAT] = run;
    run += d2; o[2 * FEAT] = run;
    run += d3; o[3 * FEAT] = run;
    run += d4; o[4 * FEAT] = run;
    run += d5; o[5 * FEAT] = run;
    run += d6; o[6 * FEAT] = run;
    run += d7; o[7 * FEAT] = run;
}

extern "C" void kernel_launch(void* const* d_in, const int* in_sizes, int n_in,
                              void* d_out, int out_size, void* d_ws, size_t ws_size,
                              hipStream_t stream) {
    (void)in_sizes; (void)n_in; (void)out_size; (void)ws_size;
    const float* emb     = (const float*)d_in[0];
    const int* starts    = (const int*)d_in[1];
    const int* ends      = (const int*)d_in[2];
    const int* num_nodes = (const int*)d_in[3];
    float* out           = (float*)d_out;

    // workspace: [sflag 2KB + pad][colsum 1MB][supersum 32KB][evcnt][evbuf (fallback)]
    int* sflag      = (int*)d_ws;
    float* colsum   = (float*)(sflag + NSUPER * FLAG_STRIDE + FLAG_PAD);
    float* supersum = colsum + (size_t)NCHUNKS * FEAT;
    int* evcnt      = (int*)(supersum + (size_t)NSUPER * FEAT);   // fallback only
    int* evbuf      = evcnt + NCHUNKS;                            // fallback only

    // Gate: K2's 32-wide flag edge needs all 1024 blocks schedulable without
    // waiting on unscheduled waiters (K2 has no LDS -> 8 blocks/CU expected).
    static int s_ok = -1;
    if (s_ok < 0) {
        int nb = 0;
        hipError_t oe = hipOccupancyMaxActiveBlocksPerMultiprocessor(&nb, k2_scan, FEAT, 0);
        s_ok = (oe == hipSuccess && nb * 256 >= NCHUNKS) ? 1 : 0;
    }

    if (s_ok == 1) {
        k1_classify<<<NCHUNKS, FEAT, 0, stream>>>(
            emb, starts, ends, num_nodes, colsum, sflag, out);
        k2_scan<<<NCHUNKS, FEAT, 0, stream>>>(colsum, supersum, sflag, out);
        return;
    }

    // Fallback: verified 3-dispatch pipeline.
    hipMemsetAsync(supersum, 0, (size_t)NSUPER * FEAT * sizeof(float), stream);
    classify_colsum_kernel<<<NCHUNKS, FEAT, 0, stream>>>(
        emb, starts, ends, num_nodes, colsum, supersum, evcnt, evbuf);
    scan_kernel<<<NCHUNKS, FEAT, 0, stream>>>(
        emb, colsum, supersum, evcnt, evbuf, out);
}

// Round 5
// 109.656 us; speedup vs baseline: 1.0225x; 1.0225x over previous
//
#include <hip/hip_runtime.h>

#define T_TOKENS 8192
#define MAX_NODES 8192
#define FEAT 256
#define NCHUNKS 1024
#define CHUNK 8                  // T_TOKENS / NCHUNKS
#define NSUPER 32
#define SUPER 32                 // chunks per supergroup
#define LIST_CAP 2048            // events/chunk cap (expected ~18, huge margin)
#define FLAG_STRIDE 16           // one flag per 64B line
#define FLAG_MAGIC 0x1B7F00D5    // bytes all distinct -> can't equal repeated-byte poison
#define FLAG_PAD 64

// entry = (node << 4) | (local_row << 1) | sign, local_row in [0,8)
#define APPLY_EVENT(eV, vV)                          \
    {                                                \
        const float sv_ = ((eV) & 1) ? -(vV) : (vV); \
        const int lr_ = ((eV) >> 1) & 7;             \
        d0 += (lr_ == 0) ? sv_ : 0.f;                \
        d1 += (lr_ == 1) ? sv_ : 0.f;                \
        d2 += (lr_ == 2) ? sv_ : 0.f;                \
        d3 += (lr_ == 3) ? sv_ : 0.f;                \
        d4 += (lr_ == 4) ? sv_ : 0.f;                \
        d5 += (lr_ == 5) ? sv_ : 0.f;                \
        d6 += (lr_ == 6) ? sv_ : 0.f;                \
        d7 += (lr_ == 7) ? sv_ : 0.f;                \
    }

// column-f sum over n rows of [n][FEAT], plain loads, 8 in flight
__device__ __forceinline__ float sum_rows_plain(const float* p, int n, int f) {
    float r0 = 0.f, r1 = 0.f, r2 = 0.f, r3 = 0.f;
    float r4 = 0.f, r5 = 0.f, r6 = 0.f, r7 = 0.f;
    int i = 0;
    for (; i + 8 <= n; i += 8) {
        r0 += p[(size_t)(i + 0) * FEAT + f];
        r1 += p[(size_t)(i + 1) * FEAT + f];
        r2 += p[(size_t)(i + 2) * FEAT + f];
        r3 += p[(size_t)(i + 3) * FEAT + f];
        r4 += p[(size_t)(i + 4) * FEAT + f];
        r5 += p[(size_t)(i + 5) * FEAT + f];
        r6 += p[(size_t)(i + 6) * FEAT + f];
        r7 += p[(size_t)(i + 7) * FEAT + f];
    }
    for (; i < n; ++i) r0 += p[(size_t)i * FEAT + f];
    return ((r0 + r1) + (r2 + r3)) + ((r4 + r5) + (r6 + r7));
}

// ---------------------------------------------------------------------------
// K1: classify + gather-once + local cumsum + supersum accumulation.
//  - lc==0 blocks zero supersum[sg] FIRST, then release a padded flag
//    (magic value, poison-proof). With preset!=0 (fallback: host memset did
//    the zeroing) all flag logic is skipped.
//  - all blocks: classify 6 rounds -> event list in LDS -> gather ~18 signed
//    emb rows ONCE into d0..d7 -> colsum[c] + chunk-local cumsum into out.
//  - tail: RELAXED spin on group flag (set ~8us earlier; one load typical),
//    ONE acquire fence, then atomicAdd csum into supersum[sg].
// Cross-block edge is 32-wide, backward (lc==0 is the lowest ID of each
// group), all 1024 blocks co-resident (gated host-side).
// ---------------------------------------------------------------------------
__global__ __launch_bounds__(FEAT) void k1_classify(
    const float* __restrict__ emb,
    const int* __restrict__ starts,
    const int* __restrict__ ends,
    const int* __restrict__ num_nodes_p,
    float* __restrict__ colsum,
    float* __restrict__ supersum,
    int* __restrict__ sflag,
    float* __restrict__ out,
    int preset) {
    __shared__ int s_list[LIST_CAP];   // 8 KB
    __shared__ int s_cnt;
    const int c = blockIdx.x;
    const int tid = threadIdx.x;
    const int f = tid;
    const int sg = c >> 5;
    const int lc = c & 31;
    const int num_nodes = *num_nodes_p;
    const int row_lo = c * CHUNK;
    const int row_hi = row_lo + CHUNK;
    const int4* starts4 = (const int4*)starts;
    const int4* ends4 = (const int4*)ends;

    // group leader zeroes its supersum row, then releases the padded flag
    if (!preset && lc == 0) {
        supersum[(size_t)sg * FEAT + f] = 0.f;
        __syncthreads();   // vmcnt(0) drain before the release store
        if (tid == 0)
            __hip_atomic_store(&sflag[sg * FLAG_STRIDE], FLAG_MAGIC,
                               __ATOMIC_RELEASE, __HIP_MEMORY_SCOPE_AGENT);
    }

    if (tid == 0) s_cnt = 0;
    __syncthreads();
    const int R = min(MAX_NODES / (4 * FEAT), (num_nodes + 1023) >> 10);
    for (int r = 0; r < R; ++r) {
        const int vec = r * FEAT + tid;
        const int4 s4 = starts4[vec];
        const int4 e4 = ends4[vec];
        const int sv[4] = {s4.x, s4.y, s4.z, s4.w};
        const int ev[4] = {e4.x, e4.y, e4.z, e4.w};
        const int nb = vec * 4;
#pragma unroll
        for (int k = 0; k < 4; ++k) {
            const int node = nb + k;
            const int s = sv[k];
            const int e = ev[k];
            if (node < num_nodes && s <= e && s < T_TOKENS && e >= 0) {
                const int sc = s < 0 ? 0 : s;
                if (sc >= row_lo && sc < row_hi) {
                    int p = atomicAdd(&s_cnt, 1);
                    if (p < LIST_CAP) s_list[p] = (node << 4) | ((sc - row_lo) << 1);
                }
                const int e1 = e + 1;
                if (e1 < T_TOKENS && e1 >= row_lo && e1 < row_hi) {
                    int p = atomicAdd(&s_cnt, 1);
                    if (p < LIST_CAP) s_list[p] = (node << 4) | ((e1 - row_lo) << 1) | 1;
                }
            }
        }
    }
    __syncthreads();
    const int cnt = min(s_cnt, LIST_CAP);

    float d0 = 0.f, d1 = 0.f, d2 = 0.f, d3 = 0.f;
    float d4 = 0.f, d5 = 0.f, d6 = 0.f, d7 = 0.f;
    {
        int j = 0;
        for (; j + 8 <= cnt; j += 8) {
            const int e0 = s_list[j + 0], e1 = s_list[j + 1];
            const int e2 = s_list[j + 2], e3 = s_list[j + 3];
            const int e4_ = s_list[j + 4], e5 = s_list[j + 5];
            const int e6 = s_list[j + 6], e7 = s_list[j + 7];
            const float v0 = emb[(size_t)(e0 >> 4) * FEAT + f];
            const float v1 = emb[(size_t)(e1 >> 4) * FEAT + f];
            const float v2 = emb[(size_t)(e2 >> 4) * FEAT + f];
            const float v3 = emb[(size_t)(e3 >> 4) * FEAT + f];
            const float v4 = emb[(size_t)(e4_ >> 4) * FEAT + f];
            const float v5 = emb[(size_t)(e5 >> 4) * FEAT + f];
            const float v6 = emb[(size_t)(e6 >> 4) * FEAT + f];
            const float v7 = emb[(size_t)(e7 >> 4) * FEAT + f];
            APPLY_EVENT(e0, v0);
            APPLY_EVENT(e1, v1);
            APPLY_EVENT(e2, v2);
            APPLY_EVENT(e3, v3);
            APPLY_EVENT(e4_, v4);
            APPLY_EVENT(e5, v5);
            APPLY_EVENT(e6, v6);
            APPLY_EVENT(e7, v7);
        }
        for (; j < cnt; ++j) {
            const int e0 = s_list[j];
            const float v0 = emb[(size_t)(e0 >> 4) * FEAT + f];
            APPLY_EVENT(e0, v0);
        }
    }
    const float csum = ((d0 + d1) + (d2 + d3)) + ((d4 + d5) + (d6 + d7));
    colsum[(size_t)c * FEAT + f] = csum;

    // chunk-local cumsum straight into out (K2 adds the global prefix)
    float* o = out + (size_t)c * CHUNK * FEAT + f;
    float run = 0.f;
    run += d0; o[0 * FEAT] = run;
    run += d1; o[1 * FEAT] = run;
    run += d2; o[2 * FEAT] = run;
    run += d3; o[3 * FEAT] = run;
    run += d4; o[4 * FEAT] = run;
    run += d5; o[5 * FEAT] = run;
    run += d6; o[6 * FEAT] = run;
    run += d7; o[7 * FEAT] = run;

    // fold csum into supersum[sg]; zeroing happened ~8us ago -> spin is 1 load
    if (!preset) {
        // RELAXED poll (no per-iteration cache invalidation!), one fence after
        while (__hip_atomic_load(&sflag[sg * FLAG_STRIDE],
                                 __ATOMIC_RELAXED, __HIP_MEMORY_SCOPE_AGENT) != FLAG_MAGIC)
            __builtin_amdgcn_s_sleep(2);
        __builtin_amdgcn_fence(__ATOMIC_ACQUIRE, "agent");
    }
    atomicAdd(&supersum[(size_t)sg * FEAT + f], csum);
}

// ---------------------------------------------------------------------------
// K2: prefix + apply. No LDS, no flags, no atomics — supersum/colsum are
// complete at the kernel boundary. Block c: run = sum(supersum[<sg]) +
// sum(in-group colsum[<lc])  (<=62 rows), then out[row] += run.
// ---------------------------------------------------------------------------
__global__ __launch_bounds__(FEAT) void k2_scan(
    const float* __restrict__ colsum,
    const float* __restrict__ supersum,
    float* __restrict__ out) {
    const int c = blockIdx.x;
    const int f = threadIdx.x;
    const int sg = c >> 5;
    const int lc = c & 31;

    const float run = sum_rows_plain(supersum, sg, f) +
                      sum_rows_plain(colsum + (size_t)sg * SUPER * FEAT, lc, f);

    float* o = out + (size_t)c * CHUNK * FEAT + f;
    const float v0 = o[0 * FEAT];
    const float v1 = o[1 * FEAT];
    const float v2 = o[2 * FEAT];
    const float v3 = o[3 * FEAT];
    const float v4 = o[4 * FEAT];
    const float v5 = o[5 * FEAT];
    const float v6 = o[6 * FEAT];
    const float v7 = o[7 * FEAT];
    o[0 * FEAT] = run + v0;
    o[1 * FEAT] = run + v1;
    o[2 * FEAT] = run + v2;
    o[3 * FEAT] = run + v3;
    o[4 * FEAT] = run + v4;
    o[5 * FEAT] = run + v5;
    o[6 * FEAT] = run + v6;
    o[7 * FEAT] = run + v7;
}

extern "C" void kernel_launch(void* const* d_in, const int* in_sizes, int n_in,
                              void* d_out, int out_size, void* d_ws, size_t ws_size,
                              hipStream_t stream) {
    (void)in_sizes; (void)n_in; (void)out_size; (void)ws_size;
    const float* emb     = (const float*)d_in[0];
    const int* starts    = (const int*)d_in[1];
    const int* ends      = (const int*)d_in[2];
    const int* num_nodes = (const int*)d_in[3];
    float* out           = (float*)d_out;

    // workspace: [sflag 2KB + pad][colsum 1MB][supersum 32KB]
    int* sflag      = (int*)d_ws;
    float* colsum   = (float*)(sflag + NSUPER * FLAG_STRIDE + FLAG_PAD);
    float* supersum = colsum + (size_t)NCHUNKS * FEAT;

    // Gate: K1's 32-wide zero-init flag edge needs all 1024 blocks resident
    // (K1: 8KB LDS, ~40 VGPR -> expect >=4 blocks/CU).
    static int s_ok = -1;
    if (s_ok < 0) {
        int nb = 0;
        hipError_t oe = hipOccupancyMaxActiveBlocksPerMultiprocessor(&nb, k1_classify, FEAT, 0);
        s_ok = (oe == hipSuccess && nb >= 4) ? 1 : 0;
    }

    if (s_ok == 1) {
        // 2 dispatches: in-K1 zero-init (flags), kernel boundary for the wide edge
        k1_classify<<<NCHUNKS, FEAT, 0, stream>>>(
            emb, starts, ends, num_nodes, colsum, supersum, sflag, out, /*preset=*/0);
        k2_scan<<<NCHUNKS, FEAT, 0, stream>>>(colsum, supersum, out);
        return;
    }

    // Fallback: identical kernels, host memset does the zero-init (3 dispatches).
    (void)hipMemsetAsync(supersum, 0, (size_t)NSUPER * FEAT * sizeof(float), stream);
    k1_classify<<<NCHUNKS, FEAT, 0, stream>>>(
        emb, starts, ends, num_nodes, colsum, supersum, sflag, out, /*preset=*/1);
    k2_scan<<<NCHUNKS, FEAT, 0, stream>>>(colsum, supersum, out);
}

// Round 6
// 82.522 us; speedup vs baseline: 1.3587x; 1.3288x over previous
//
#include <hip/hip_runtime.h>

#define T_TOKENS 8192
#define MAX_NODES 8192
#define FEAT 256
#define NCHUNKS 1024
#define CHUNK 8                  // T_TOKENS / NCHUNKS
#define NSUPER 32
#define SUPER 32                 // chunks per supergroup
#define LIST_CAP 2048            // events/chunk cap (expected ~18, huge margin)
#define EV_STRIDE LIST_CAP

// entry = (node << 4) | (local_row << 1) | sign, local_row in [0,8)
#define APPLY_EVENT(eV, vV)                          \
    {                                                \
        const float sv_ = ((eV) & 1) ? -(vV) : (vV); \
        const int lr_ = ((eV) >> 1) & 7;             \
        d0 += (lr_ == 0) ? sv_ : 0.f;                \
        d1 += (lr_ == 1) ? sv_ : 0.f;                \
        d2 += (lr_ == 2) ? sv_ : 0.f;                \
        d3 += (lr_ == 3) ? sv_ : 0.f;                \
        d4 += (lr_ == 4) ? sv_ : 0.f;                \
        d5 += (lr_ == 5) ? sv_ : 0.f;                \
        d6 += (lr_ == 6) ? sv_ : 0.f;                \
        d7 += (lr_ == 7) ? sv_ : 0.f;                \
    }

// column-f sum over n rows of [n][FEAT], plain loads, 8 in flight
__device__ __forceinline__ float sum_rows_plain(const float* __restrict__ p, int n, int f) {
    float r0 = 0.f, r1 = 0.f, r2 = 0.f, r3 = 0.f;
    float r4 = 0.f, r5 = 0.f, r6 = 0.f, r7 = 0.f;
    int i = 0;
    for (; i + 8 <= n; i += 8) {
        r0 += p[(size_t)(i + 0) * FEAT + f];
        r1 += p[(size_t)(i + 1) * FEAT + f];
        r2 += p[(size_t)(i + 2) * FEAT + f];
        r3 += p[(size_t)(i + 3) * FEAT + f];
        r4 += p[(size_t)(i + 4) * FEAT + f];
        r5 += p[(size_t)(i + 5) * FEAT + f];
        r6 += p[(size_t)(i + 6) * FEAT + f];
        r7 += p[(size_t)(i + 7) * FEAT + f];
    }
    for (; i < n; ++i) r0 += p[(size_t)i * FEAT + f];
    return ((r0 + r1) + (r2 + r3)) + ((r4 + r5) + (r6 + r7));
}

// ---------------------------------------------------------------------------
// K1: classify + colsum. Proven round-0 structure. NO atomics to global,
// NO fences, NO flags. Differences vs round-0:
//  - each fully-unrolled round is guarded by a scalar `nb < num_nodes`
//    branch, skipping rounds with no valid nodes (6000 -> 2 of 8 skipped)
//  - no supersum atomicAdd tail (K-mid builds supersum instead)
// ---------------------------------------------------------------------------
__global__ __launch_bounds__(FEAT) void classify_kernel(
    const float* __restrict__ emb,
    const int* __restrict__ starts,
    const int* __restrict__ ends,
    const int* __restrict__ num_nodes_p,
    float* __restrict__ colsum,
    int* __restrict__ evcnt,
    int* __restrict__ evbuf) {
    __shared__ int s_list[LIST_CAP];   // 8 KB
    __shared__ int s_cnt;
    const int c = blockIdx.x;
    const int tid = threadIdx.x;
    const int f = tid;
    const int num_nodes = *num_nodes_p;
    const int row_lo = c * CHUNK;
    const int row_hi = row_lo + CHUNK;
    const int4* starts4 = (const int4*)starts;
    const int4* ends4 = (const int4*)ends;

    if (tid == 0) s_cnt = 0;
    __syncthreads();
#pragma unroll
    for (int r = 0; r < MAX_NODES / (4 * FEAT); ++r) {   // 8 rounds x 1024 nodes
        if (r * 4 * FEAT < num_nodes) {                  // scalar skip of empty rounds
            const int vec = r * FEAT + tid;
            const int4 s4 = starts4[vec];
            const int4 e4 = ends4[vec];
            const int sv[4] = {s4.x, s4.y, s4.z, s4.w};
            const int ev[4] = {e4.x, e4.y, e4.z, e4.w};
            const int nb = vec * 4;
#pragma unroll
            for (int k = 0; k < 4; ++k) {
                const int node = nb + k;
                const int s = sv[k];
                const int e = ev[k];
                if (node < num_nodes && s <= e && s < T_TOKENS && e >= 0) {
                    const int sc = s < 0 ? 0 : s;
                    if (sc >= row_lo && sc < row_hi) {
                        int p = atomicAdd(&s_cnt, 1);
                        if (p < LIST_CAP) s_list[p] = (node << 4) | ((sc - row_lo) << 1);
                    }
                    const int e1 = e + 1;
                    if (e1 < T_TOKENS && e1 >= row_lo && e1 < row_hi) {
                        int p = atomicAdd(&s_cnt, 1);
                        if (p < LIST_CAP) s_list[p] = (node << 4) | ((e1 - row_lo) << 1) | 1;
                    }
                }
            }
        }
    }
    __syncthreads();
    const int cnt = min(s_cnt, LIST_CAP);

    // flush events to global (coalesced; ~18 ints typical)
    int* evb = evbuf + (size_t)c * EV_STRIDE;
    for (int j = tid; j < cnt; j += FEAT) evb[j] = s_list[j];
    if (tid == 0) evcnt[c] = cnt;

    // gather signed emb rows, 8 loads in flight
    float acc = 0.f;
    int j = 0;
    for (; j + 8 <= cnt; j += 8) {
        const int e0 = s_list[j + 0], e1 = s_list[j + 1];
        const int e2 = s_list[j + 2], e3 = s_list[j + 3];
        const int e4_ = s_list[j + 4], e5 = s_list[j + 5];
        const int e6 = s_list[j + 6], e7 = s_list[j + 7];
        const float v0 = emb[(size_t)(e0 >> 4) * FEAT + f];
        const float v1 = emb[(size_t)(e1 >> 4) * FEAT + f];
        const float v2 = emb[(size_t)(e2 >> 4) * FEAT + f];
        const float v3 = emb[(size_t)(e3 >> 4) * FEAT + f];
        const float v4 = emb[(size_t)(e4_ >> 4) * FEAT + f];
        const float v5 = emb[(size_t)(e5 >> 4) * FEAT + f];
        const float v6 = emb[(size_t)(e6 >> 4) * FEAT + f];
        const float v7 = emb[(size_t)(e7 >> 4) * FEAT + f];
        acc += (e0 & 1) ? -v0 : v0;
        acc += (e1 & 1) ? -v1 : v1;
        acc += (e2 & 1) ? -v2 : v2;
        acc += (e3 & 1) ? -v3 : v3;
        acc += (e4_ & 1) ? -v4 : v4;
        acc += (e5 & 1) ? -v5 : v5;
        acc += (e6 & 1) ? -v6 : v6;
        acc += (e7 & 1) ? -v7 : v7;
    }
    for (; j < cnt; ++j) {
        const int e0 = s_list[j];
        const float v0 = emb[(size_t)(e0 >> 4) * FEAT + f];
        acc += (e0 & 1) ? -v0 : v0;
    }
    colsum[(size_t)c * FEAT + f] = acc;
}

// ---------------------------------------------------------------------------
// K-mid: 32 blocks; block g OVERWRITES supersum[g] = sum of its 32 colsum
// rows. Replaces {memset + 262k device atomicAdds}. Pure overwrite ->
// no zero-init, no atomics, no fences. ~1 MB of reads total.
// ---------------------------------------------------------------------------
__global__ __launch_bounds__(FEAT) void super_kernel(
    const float* __restrict__ colsum,
    float* __restrict__ supersum) {
    const int g = blockIdx.x;
    const int f = threadIdx.x;
    supersum[(size_t)g * FEAT + f] =
        sum_rows_plain(colsum + (size_t)g * SUPER * FEAT, SUPER, f);
}

// ---------------------------------------------------------------------------
// K2: scan — verbatim round-0 (proven): 2-level exclusive prefix (8 loads in
// flight), replay event list from evbuf into 8 register rows, scan + store.
// ---------------------------------------------------------------------------
__global__ __launch_bounds__(FEAT) void scan_kernel(
    const float* __restrict__ emb,
    const float* __restrict__ colsum,
    const float* __restrict__ supersum,
    const int* __restrict__ evcnt,
    const int* __restrict__ evbuf,
    float* __restrict__ out) {
    const int c = blockIdx.x;
    const int f = threadIdx.x;
    const int sg = c >> 5;

    const int cnt = evcnt[c];
    const int* evb = evbuf + (size_t)c * EV_STRIDE;

    float run = sum_rows_plain(supersum, sg, f) +
                sum_rows_plain(colsum + (size_t)sg * SUPER * FEAT, c & 31, f);

    float d0 = 0.f, d1 = 0.f, d2 = 0.f, d3 = 0.f;
    float d4 = 0.f, d5 = 0.f, d6 = 0.f, d7 = 0.f;
    int j = 0;
    for (; j + 4 <= cnt; j += 4) {
        const int e0 = evb[j + 0], e1 = evb[j + 1];
        const int e2 = evb[j + 2], e3 = evb[j + 3];
        const float v0 = emb[(size_t)(e0 >> 4) * FEAT + f];
        const float v1 = emb[(size_t)(e1 >> 4) * FEAT + f];
        const float v2 = emb[(size_t)(e2 >> 4) * FEAT + f];
        const float v3 = emb[(size_t)(e3 >> 4) * FEAT + f];
        APPLY_EVENT(e0, v0);
        APPLY_EVENT(e1, v1);
        APPLY_EVENT(e2, v2);
        APPLY_EVENT(e3, v3);
    }
    for (; j < cnt; ++j) {
        const int e0 = evb[j];
        const float v0 = emb[(size_t)(e0 >> 4) * FEAT + f];
        APPLY_EVENT(e0, v0);
    }

    float* o = out + (size_t)c * CHUNK * FEAT + f;
    run += d0; o[0 * FEAT] = run;
    run += d1; o[1 * FEAT] = run;
    run += d2; o[2 * FEAT] = run;
    run += d3; o[3 * FEAT] = run;
    run += d4; o[4 * FEAT] = run;
    run += d5; o[5 * FEAT] = run;
    run += d6; o[6 * FEAT] = run;
    run += d7; o[7 * FEAT] = run;
}

extern "C" void kernel_launch(void* const* d_in, const int* in_sizes, int n_in,
                              void* d_out, int out_size, void* d_ws, size_t ws_size,
                              hipStream_t stream) {
    (void)in_sizes; (void)n_in; (void)out_size; (void)ws_size;
    const float* emb     = (const float*)d_in[0];
    const int* starts    = (const int*)d_in[1];
    const int* ends      = (const int*)d_in[2];
    const int* num_nodes = (const int*)d_in[3];
    float* out           = (float*)d_out;

    // workspace: [colsum 1MB][supersum 32KB][evcnt 4KB][evbuf 8MB]
    float* colsum   = (float*)d_ws;
    float* supersum = colsum + (size_t)NCHUNKS * FEAT;
    int* evcnt      = (int*)(supersum + (size_t)NSUPER * FEAT);
    int* evbuf      = evcnt + NCHUNKS;

    // Pure forward dataflow through kernel boundaries. No atomics, no flags,
    // no fences, no memset. Deadlock-free by construction.
    classify_kernel<<<NCHUNKS, FEAT, 0, stream>>>(
        emb, starts, ends, num_nodes, colsum, evcnt, evbuf);
    super_kernel<<<NSUPER, FEAT, 0, stream>>>(colsum, supersum);
    scan_kernel<<<NCHUNKS, FEAT, 0, stream>>>(
        emb, colsum, supersum, evcnt, evbuf, out);
}